// Round 10
// baseline (78.664 us; speedup 1.0000x reference)
//
#include <hip/hip_runtime.h>

#define BB 65536
#define TT 20
#define NE 2048               // 32-element blocks
#define FRAG_T 160            // u32 per timestep per block (h as B-fragments)

#define WS_WGT 0              // 14 frags x 64 lanes x 4 u32
#define WS_HF0 4096
#define WS_HB0 (WS_HF0 + NE * TT * FRAG_T)
#define WS_END (WS_HB0 + NE * TT * FRAG_T)
#define PK1 0x00003C00u       // f16 pair {1.0, 0.0}

#define LOG2E  1.442695041f
#define LOG2E2 2.885390082f

typedef unsigned u32;
typedef __fp16 f16x8 __attribute__((ext_vector_type(8)));
typedef float   f32x16 __attribute__((ext_vector_type(16)));
typedef u32     u32x4 __attribute__((ext_vector_type(4)));
typedef __fp16  h2v   __attribute__((ext_vector_type(2)));

__device__ __forceinline__ u32 pk_h16(float a, float b) {
    h2v v = __builtin_amdgcn_cvt_pkrtz(a, b);
    return __builtin_bit_cast(u32, v);
}
__device__ __forceinline__ f32x16 MFMA(u32x4 a, u32x4 b, f32x16 c) {
    return __builtin_amdgcn_mfma_f32_32x32x16_f16(
        __builtin_bit_cast(f16x8, a), __builtin_bit_cast(f16x8, b), c, 0, 0, 0);
}

// Combined-rcp LSTM unit (8 trans ops/unit).
__device__ __forceinline__ void unit_cr(float ai, float af, float ag, float ao,
                                        float* c, float* h) {
    float pi = __builtin_amdgcn_exp2f(-LOG2E * ai);
    float pf = __builtin_amdgcn_exp2f(-LOG2E * af);
    float q  = __builtin_amdgcn_exp2f(LOG2E2 * ag);
    float fv = __builtin_amdgcn_rcpf(1.0f + pf);
    float ig = (q - 1.0f) * __builtin_amdgcn_rcpf((1.0f + pi) * (q + 1.0f));
    float cv = fmaf(fv, *c, ig);
    *c = cv;
    float po = __builtin_amdgcn_exp2f(-LOG2E * ao);
    float qc = __builtin_amdgcn_exp2f(LOG2E2 * cv);
    *h = (qc - 1.0f) * __builtin_amdgcn_rcpf((1.0f + po) * (qc + 1.0f));
}

// h-input B-fragment; k = 4g+{0..3} U 8+4g+{0..3}.  One bpermute/pack.
__device__ __forceinline__ u32x4 pack_h(const float* h, bool hi, int xaddr, u32 b3) {
    u32 send = hi ? pk_h16(h[3], h[4]) : __float_as_uint(h[4]);
    u32 recv = (u32)__builtin_amdgcn_ds_bpermute(xaddr, (int)send);
    u32 lo0 = pk_h16(h[0], h[1]), lo1 = pk_h16(h[2], h[3]);
    u32 hi0 = pk_h16(__uint_as_float(recv), h[0]);   // {h4, h5}
    u32 hi1 = pk_h16(h[1], h[2]);                    // {h6, h7}
    u32x4 b;
    b[0] = hi ? hi0 : lo0;
    b[1] = hi ? hi1 : lo1;
    b[2] = hi ? 0u : recv;                           // {h8, h9} on g0
    b[3] = b3;
    return b;
}

// C layout (verified): row=(r&3)+8*(r>>2)+4*(lane>>5); row perm pi(q,u=5h+v).
__device__ __forceinline__ void cell_update5(const f32x16 a0, const f32x16 a1,
                                             float* c, float* h) {
#pragma unroll
    for (int v = 0; v < 4; ++v)
        unit_cr(a0[v], a0[4 + v], a0[8 + v], a0[12 + v], &c[v], &h[v]);
    unit_cr(a1[0], a1[1], a1[2], a1[3], &c[4], &h[4]);
}

// ---------------- prep: build A-fragments (weights, permuted rows) ----------------
__device__ __forceinline__ int inv_pi(int row) {
    if (row < 32) { int q = row >> 3, rem = row & 7; return q * 10 + 5 * (rem >> 2) + (rem & 3); }
    if (row < 40) { int lo = row - 32; return (lo & 3) * 10 + 5 * (lo >> 2) + 4; }
    return -1;
}

__global__ __launch_bounds__(256)
void prep_mfma(
    const float* __restrict__ wih0, const float* __restrict__ whh0,
    const float* __restrict__ bih0, const float* __restrict__ bhh0,
    const float* __restrict__ wih0r,const float* __restrict__ whh0r,
    const float* __restrict__ bih0r,const float* __restrict__ bhh0r,
    const float* __restrict__ wih1r,const float* __restrict__ whh1r,
    const float* __restrict__ bih1r,const float* __restrict__ bhh1r,
    u32* __restrict__ ws)
{
    for (int gid = threadIdx.x; gid < 14 * 64 * 4; gid += 256) {
        int fid = gid >> 8, l = (gid >> 2) & 63, j = gid & 3;
        int g = l >> 5;
        int tile, chunk;
        if (fid < 8) { tile = (fid >> 1) & 1; chunk = fid & 1; }
        else         { int q = fid - 8; tile = q / 3; chunk = q % 3; }
        int row = tile * 32 + (l & 31);
        int orow = inv_pi(row);
        int kb = (j >> 1) * 8 + 4 * g + (j & 1) * 2;
        float v[2] = {0.f, 0.f};
        if (orow >= 0) {
#pragma unroll
            for (int s = 0; s < 2; ++s) {
                int k = kb + s;
                float val = 0.f;
                if (fid < 8) {
                    bool bwd = fid >= 4;
                    if (chunk == 0) {
                        if (k < 6)       val = (bwd ? wih0r : wih0)[orow * 6 + k];
                        else if (k == 6) val = (bwd ? bih0r[orow] + bhh0r[orow]
                                                    : bih0[orow] + bhh0[orow]);
                    } else {
                        if (k < 10)      val = (bwd ? whh0r : whh0)[orow * 10 + k];
                    }
                } else {
                    if (chunk == 0)      { if (k < 10) val = wih1r[orow * 20 + k]; }
                    else if (chunk == 1) { if (k < 10) val = wih1r[orow * 20 + 10 + k]; }
                    else {
                        if (k < 10)      val = whh1r[orow * 10 + k];
                        else if (k == 10) val = bih1r[orow] + bhh1r[orow];
                    }
                }
                v[s] = val;
            }
        }
        ws[WS_WGT + (fid * 64 + l) * 4 + j] = pk_h16(v[0], v[1]);
    }
}

// ---------------- Kernel L0: fwd (wid<NE) or bwd (wid>=NE) layer-0 chain ----------------
__global__ __launch_bounds__(64)
void bilstm_l0(
    const int*   __restrict__ eidx, const float* __restrict__ f,
    const float* __restrict__ emb,  const float* __restrict__ fw,
    const float* __restrict__ fb,
    const u32* __restrict__ wsr, u32* __restrict__ ghf, u32* __restrict__ ghb)
{
    __shared__ u32 xs[TT][3][32];
    const int  lane = threadIdx.x;
    const int  e    = lane & 31;
    const bool hi   = lane >= 32;
    const int  wid  = blockIdx.x;
    const int  dir  = wid >> 11;         // 0 = fwd, 1 = bwd
    const int  eb   = wid & (NE - 1);
    const int  b0   = eb * 32;
    const int  xaddr = (lane ^ 32) << 2;

    // stage x
    {
        float fw0=fw[0],fw1=fw[1],fw2=fw[2],fw3=fw[3],fw4=fw[4];
        float fw5=fw[5],fw6=fw[6],fw7=fw[7],fw8=fw[8];
        float fb0=fb[0],fb1=fb[1],fb2=fb[2];
#pragma unroll 1
        for (int it = 0; it < 10; ++it) {
            int idx = lane + it * 64;
            int ee = idx / 20, t = idx - ee * 20;
            int gi = (b0 + ee) * TT + t;
            float f0 = f[gi * 3], f1 = f[gi * 3 + 1], f2v = f[gi * 3 + 2];
            int ei = eidx[gi] * 3;
            float x0 = emb[ei], x1 = emb[ei + 1], x2 = emb[ei + 2];
            float x3 = fmaf(fw0, f0, fmaf(fw1, f1, fmaf(fw2, f2v, fb0)));
            float x4 = fmaf(fw3, f0, fmaf(fw4, f1, fmaf(fw5, f2v, fb1)));
            float x5 = fmaf(fw6, f0, fmaf(fw7, f1, fmaf(fw8, f2v, fb2)));
            xs[t][0][ee] = pk_h16(x0, x1);
            xs[t][1][ee] = pk_h16(x2, x3);
            xs[t][2][ee] = pk_h16(x4, x5);
        }
    }

    const u32x4* wv = (const u32x4*)wsr;
    const f32x16 zf = {};
    u32* outp = (dir ? ghb : ghf) + (size_t)eb * TT * FRAG_T;
    const int wbase = dir ? 4 : 0;
    u32x4 w0 = wv[(wbase + 0) * 64 + lane], w1 = wv[(wbase + 1) * 64 + lane];
    u32x4 w2 = wv[(wbase + 2) * 64 + lane], w3 = wv[(wbase + 3) * 64 + lane];

    auto BX = [&](int t) {
        u32 x01 = xs[t][0][e], x23 = xs[t][1][e], x45 = xs[t][2][e];
        u32x4 b; b[0] = hi ? x45 : x01; b[1] = hi ? PK1 : x23; b[2] = 0u; b[3] = 0u;
        return b;
    };

    float cst[5] = {0,0,0,0,0}, hv[5] = {0,0,0,0,0};
    const int t0 = dir ? TT - 1 : 0;
    const int dt = dir ? -1 : 1;
    f32x16 a0x = MFMA(w0, BX(t0), zf);
    f32x16 a1x = MFMA(w2, BX(t0), zf);
    u32x4 bh;
#pragma unroll 1
    for (int s = 0; s < TT; ++s) {
        const int t = t0 + s * dt;
        f32x16 a0 = a0x, a1 = a1x;
        if (s > 0) { a0 = MFMA(w1, bh, a0); a1 = MFMA(w3, bh, a1); }   // h(prev) part
        if (s + 1 < TT) {                     // prefetch next x+bias contribution
            u32x4 bx = BX(t + dt);
            a0x = MFMA(w0, bx, zf);
            a1x = MFMA(w2, bx, zf);
        }
        cell_update5(a0, a1, cst, hv);
        bh = pack_h(hv, hi, xaddr, 0u);       // single pack: frag for t+dt AND store
        *(uint2*)(outp + t * FRAG_T + lane * 2) = make_uint2(bh[0], bh[1]);
        if (!hi) outp[t * FRAG_T + 128 + e] = bh[2];
    }
}

// ---------------- Kernel CB: layer-1 backward chain ----------------
__global__ __launch_bounds__(64)
void bilstm_cb(
    const float* __restrict__ f, const u32* __restrict__ wsr,
    const u32* __restrict__ ghf, const u32* __restrict__ ghb,
    float* __restrict__ out)
{
    const int  lane = threadIdx.x;
    const int  e    = lane & 31;
    const bool hi   = lane >= 32;
    const int  eb   = blockIdx.x;
    const int  b0   = eb * 32;
    const int  xaddr = (lane ^ 32) << 2;
    const u32x4* wv = (const u32x4*)wsr;
    u32x4 wB0 = wv[8 * 64 + lane],  wB1 = wv[9 * 64 + lane],  wB2 = wv[10 * 64 + lane];
    u32x4 wB3 = wv[11 * 64 + lane], wB4 = wv[12 * 64 + lane], wB5 = wv[13 * 64 + lane];
    const u32* hfp = ghf + (size_t)eb * TT * FRAG_T;
    const u32* hbp = ghb + (size_t)eb * TT * FRAG_T;
    const f32x16 zf = {};
    float cc[5] = {0,0,0,0,0}, h1v[5] = {0,0,0,0,0}, tot = 0.f;

    uint2 hf2 = *(const uint2*)(hfp + (TT - 1) * FRAG_T + lane * 2);
    u32   hfw = hfp[(TT - 1) * FRAG_T + 128 + e];
    uint2 hb2 = *(const uint2*)(hbp + (TT - 1) * FRAG_T + lane * 2);
    u32   hbw = hbp[(TT - 1) * FRAG_T + 128 + e];
    float f1v = f[((b0 + e) * TT + (TT - 1)) * 3 + 1];

#pragma unroll 1
    for (int t = TT - 1; t >= 0; --t) {
        u32x4 bhf; bhf[0] = hf2.x; bhf[1] = hf2.y; bhf[2] = hi ? 0u : hfw; bhf[3] = 0u;
        u32x4 bhb; bhb[0] = hb2.x; bhb[1] = hb2.y; bhb[2] = hi ? 0u : hbw; bhb[3] = 0u;
        f32x16 B0 = MFMA(wB0, bhf, zf); B0 = MFMA(wB1, bhb, B0);
        f32x16 B1 = MFMA(wB3, bhf, zf); B1 = MFMA(wB4, bhb, B1);
        float fcur = f1v;
        if (t > 0) {                           // prefetch t-1 inputs
            hf2 = *(const uint2*)(hfp + (t - 1) * FRAG_T + lane * 2);
            hfw = hfp[(t - 1) * FRAG_T + 128 + e];
            hb2 = *(const uint2*)(hbp + (t - 1) * FRAG_T + lane * 2);
            hbw = hbp[(t - 1) * FRAG_T + 128 + e];
            f1v = f[((b0 + e) * TT + (t - 1)) * 3 + 1];
        }
        u32x4 bh1 = pack_h(h1v, hi, xaddr, hi ? 0u : PK1);
        B0 = MFMA(wB2, bh1, B0);
        B1 = MFMA(wB5, bh1, B1);
        cell_update5(B0, B1, cc, h1v);
        if (hi) {                              // unit 9 = (half1, v=4)
            float ip = fmaxf(h1v[4] * (fcur != 0.f ? 1.f : 0.f), 0.f);
            out[BB + (b0 + e) * TT + t] = ip;
            tot += ip;
        }
    }
    if (hi) out[b0 + e] = tot;
}

// ---------------- fallback: r9 single-kernel (ws too small for split) ----------------
template<bool WS> struct Lds {
    u32   x[TT][3][32];
    float m[TT][32];
    u32   hf[WS ? 1 : TT][FRAG_T];
};

template<bool WS>
__global__ __launch_bounds__(64)
void bilstm_mfma(
    const int*   __restrict__ eidx, const float* __restrict__ f,
    const float* __restrict__ emb,  const float* __restrict__ fw,
    const float* __restrict__ fb,
    const u32* __restrict__ wsr, u32* __restrict__ ghf,
    float* __restrict__ out)
{
    __shared__ Lds<WS> lds;
    const int  lane = threadIdx.x;
    const int  e    = lane & 31;
    const bool hi   = lane >= 32;
    const int  wid  = blockIdx.x;
    const int  b0   = wid * 32;
    const int  xaddr = (lane ^ 32) << 2;
    u32* hfp = ghf + (size_t)wid * TT * FRAG_T;

    {
        float fw0=fw[0],fw1=fw[1],fw2=fw[2],fw3=fw[3],fw4=fw[4];
        float fw5=fw[5],fw6=fw[6],fw7=fw[7],fw8=fw[8];
        float fb0=fb[0],fb1=fb[1],fb2=fb[2];
#pragma unroll 1
        for (int it = 0; it < 10; ++it) {
            int idx = lane + it * 64;
            int ee = idx / 20, t = idx - ee * 20;
            int gi = (b0 + ee) * TT + t;
            float f0 = f[gi * 3], f1 = f[gi * 3 + 1], f2v = f[gi * 3 + 2];
            int ei = eidx[gi] * 3;
            float x0 = emb[ei], x1 = emb[ei + 1], x2 = emb[ei + 2];
            float x3 = fmaf(fw0, f0, fmaf(fw1, f1, fmaf(fw2, f2v, fb0)));
            float x4 = fmaf(fw3, f0, fmaf(fw4, f1, fmaf(fw5, f2v, fb1)));
            float x5 = fmaf(fw6, f0, fmaf(fw7, f1, fmaf(fw8, f2v, fb2)));
            lds.x[t][0][ee] = pk_h16(x0, x1);
            lds.x[t][1][ee] = pk_h16(x2, x3);
            lds.x[t][2][ee] = pk_h16(x4, x5);
            lds.m[t][ee]    = (f1 != 0.f) ? 1.f : 0.f;
        }
    }

    const u32x4* wv = (const u32x4*)wsr;
    const f32x16 zf = {};
    {
        u32x4 wf0 = wv[0 * 64 + lane], wf1 = wv[1 * 64 + lane];
        u32x4 wf2 = wv[2 * 64 + lane], wf3 = wv[3 * 64 + lane];
        float cf[5] = {0,0,0,0,0}, hv[5] = {0,0,0,0,0};
        u32x4 bx0;
        {
            u32 x01 = lds.x[0][0][e], x23 = lds.x[0][1][e], x45 = lds.x[0][2][e];
            bx0[0] = hi ? x45 : x01; bx0[1] = hi ? PK1 : x23; bx0[2] = 0u; bx0[3] = 0u;
        }
        f32x16 a0x = MFMA(wf0, bx0, zf);
        f32x16 a1x = MFMA(wf2, bx0, zf);
        u32x4 bh;
#pragma unroll 1
        for (int t = 0; t < TT; ++t) {
            f32x16 a0 = a0x, a1 = a1x;
            if (t > 0) { a0 = MFMA(wf1, bh, a0); a1 = MFMA(wf3, bh, a1); }
            if (t + 1 < TT) {
                u32 x01 = lds.x[t+1][0][e], x23 = lds.x[t+1][1][e], x45 = lds.x[t+1][2][e];
                u32x4 bx; bx[0] = hi ? x45 : x01; bx[1] = hi ? PK1 : x23; bx[2] = 0u; bx[3] = 0u;
                a0x = MFMA(wf0, bx, zf);
                a1x = MFMA(wf2, bx, zf);
            }
            cell_update5(a0, a1, cf, hv);
            bh = pack_h(hv, hi, xaddr, 0u);
            if (WS) {
                *(uint2*)(hfp + t * FRAG_T + lane * 2) = make_uint2(bh[0], bh[1]);
                if (!hi) hfp[t * FRAG_T + 128 + e] = bh[2];
            } else {
                lds.hf[t][lane * 2] = bh[0]; lds.hf[t][lane * 2 + 1] = bh[1];
                if (!hi) lds.hf[t][128 + e] = bh[2];
            }
        }
    }
    {
        u32x4 wb0 = wv[4 * 64 + lane], wb1 = wv[5 * 64 + lane];
        u32x4 wb2 = wv[6 * 64 + lane], wb3 = wv[7 * 64 + lane];
        u32x4 wB0 = wv[8 * 64 + lane], wB1 = wv[9 * 64 + lane], wB2 = wv[10 * 64 + lane];
        u32x4 wB3 = wv[11 * 64 + lane], wB4 = wv[12 * 64 + lane], wB5 = wv[13 * 64 + lane];
        float cb[5] = {0,0,0,0,0}, hbv[5] = {0,0,0,0,0};
        float cc[5] = {0,0,0,0,0}, h1v[5] = {0,0,0,0,0};
        float tot = 0.f;
        {
            u32 x01 = lds.x[TT-1][0][e], x23 = lds.x[TT-1][1][e], x45 = lds.x[TT-1][2][e];
            u32x4 bx; bx[0] = hi ? x45 : x01; bx[1] = hi ? PK1 : x23; bx[2] = 0u; bx[3] = 0u;
            f32x16 a0 = MFMA(wb0, bx, zf);
            f32x16 a1 = MFMA(wb2, bx, zf);
            cell_update5(a0, a1, cb, hbv);
        }
        uint2 cur2; u32 curw;
        if (WS) { cur2 = *(const uint2*)(hfp + (TT-1) * FRAG_T + lane * 2);
                  curw = hfp[(TT-1) * FRAG_T + 128 + e]; }
        else    { cur2 = make_uint2(lds.hf[TT-1][lane * 2], lds.hf[TT-1][lane * 2 + 1]);
                  curw = lds.hf[TT-1][128 + e]; }
#pragma unroll 1
        for (int t = TT - 1; t >= 1; --t) {
            uint2 nxt2; u32 nxtw;
            if (WS) { nxt2 = *(const uint2*)(hfp + (t-1) * FRAG_T + lane * 2);
                      nxtw = hfp[(t-1) * FRAG_T + 128 + e]; }
            else    { nxt2 = make_uint2(lds.hf[t-1][lane * 2], lds.hf[t-1][lane * 2 + 1]);
                      nxtw = lds.hf[t-1][128 + e]; }
            u32x4 shared = pack_h(hbv, hi, xaddr, 0u);
            u32x4 bh1    = pack_h(h1v, hi, xaddr, hi ? 0u : PK1);
            u32x4 bhf; bhf[0] = cur2.x; bhf[1] = cur2.y; bhf[2] = hi ? 0u : curw; bhf[3] = 0u;
            f32x16 B0 = MFMA(wB0, bhf, zf); B0 = MFMA(wB1, shared, B0); B0 = MFMA(wB2, bh1, B0);
            f32x16 B1 = MFMA(wB3, bhf, zf); B1 = MFMA(wB4, shared, B1); B1 = MFMA(wB5, bh1, B1);
            u32 x01 = lds.x[t-1][0][e], x23 = lds.x[t-1][1][e], x45 = lds.x[t-1][2][e];
            u32x4 bx; bx[0] = hi ? x45 : x01; bx[1] = hi ? PK1 : x23; bx[2] = 0u; bx[3] = 0u;
            f32x16 A0 = MFMA(wb0, bx, zf); A0 = MFMA(wb1, shared, A0);
            f32x16 A1 = MFMA(wb2, bx, zf); A1 = MFMA(wb3, shared, A1);
            cell_update5(B0, B1, cc, h1v);
            if (hi) {
                float ip = fmaxf(h1v[4] * lds.m[t][e], 0.f);
                out[BB + (b0 + e) * TT + t] = ip;
                tot += ip;
            }
            cell_update5(A0, A1, cb, hbv);
            cur2 = nxt2; curw = nxtw;
        }
        {
            u32x4 shared = pack_h(hbv, hi, xaddr, 0u);
            u32x4 bh1    = pack_h(h1v, hi, xaddr, hi ? 0u : PK1);
            u32x4 bhf; bhf[0] = cur2.x; bhf[1] = cur2.y; bhf[2] = hi ? 0u : curw; bhf[3] = 0u;
            f32x16 B0 = MFMA(wB0, bhf, zf); B0 = MFMA(wB1, shared, B0); B0 = MFMA(wB2, bh1, B0);
            f32x16 B1 = MFMA(wB3, bhf, zf); B1 = MFMA(wB4, shared, B1); B1 = MFMA(wB5, bh1, B1);
            cell_update5(B0, B1, cc, h1v);
            if (hi) {
                float ip = fmaxf(h1v[4] * lds.m[0][e], 0.f);
                out[BB + (b0 + e) * TT + 0] = ip;
                tot += ip;
                out[b0 + e] = tot;
            }
        }
    }
}

extern "C" void kernel_launch(void* const* d_in, const int* in_sizes, int n_in,
                              void* d_out, int out_size, void* d_ws, size_t ws_size,
                              hipStream_t stream) {
    const int*   eidx  = (const int*)  d_in[0];
    const float* f     = (const float*)d_in[1];
    const float* emb   = (const float*)d_in[2];
    const float* fw    = (const float*)d_in[3];
    const float* fb    = (const float*)d_in[4];
    const float* wih0  = (const float*)d_in[5];
    const float* whh0  = (const float*)d_in[6];
    const float* bih0  = (const float*)d_in[7];
    const float* bhh0  = (const float*)d_in[8];
    const float* wih0r = (const float*)d_in[9];
    const float* whh0r = (const float*)d_in[10];
    const float* bih0r = (const float*)d_in[11];
    const float* bhh0r = (const float*)d_in[12];
    // d_in[13..16] = layer-1 forward weights: dead (output uses only bwd unit 9)
    const float* wih1r = (const float*)d_in[17];
    const float* whh1r = (const float*)d_in[18];
    const float* bih1r = (const float*)d_in[19];
    const float* bhh1r = (const float*)d_in[20];
    float* out = (float*)d_out;
    u32* ws = (u32*)d_ws;

    hipLaunchKernelGGL(prep_mfma, dim3(1), dim3(256), 0, stream,
                       wih0, whh0, bih0, bhh0, wih0r, whh0r, bih0r, bhh0r,
                       wih1r, whh1r, bih1r, bhh1r, ws);

    const size_t need_split = (size_t)WS_END * 4;
    const size_t need_r9    = (size_t)(WS_HF0 + (size_t)NE * TT * FRAG_T) * 4;
    if (ws_size >= need_split) {
        hipLaunchKernelGGL(bilstm_l0, dim3(2 * NE), dim3(64), 0, stream,
                           eidx, f, emb, fw, fb, ws, ws + WS_HF0, ws + WS_HB0);
        hipLaunchKernelGGL(bilstm_cb, dim3(NE), dim3(64), 0, stream,
                           f, ws, ws + WS_HF0, ws + WS_HB0, out);
    } else if (ws_size >= need_r9) {
        hipLaunchKernelGGL(bilstm_mfma<true>, dim3(NE), dim3(64), 0, stream,
                           eidx, f, emb, fw, fb, ws, ws + WS_HF0, out);
    } else {
        hipLaunchKernelGGL(bilstm_mfma<false>, dim3(NE), dim3(64), 0, stream,
                           eidx, f, emb, fw, fb, ws, ws + WS_HF0, out);
    }
}

// Round 11
// 71.974 us; speedup vs baseline: 1.0930x; 1.0930x over previous
//
#include <hip/hip_runtime.h>

#define BB 65536
#define TT 20
#define NE 2048               // 32-element groups
#define FRAG_T 160            // u32 per timestep per group (h as B-fragments)

#define WS_WGT 0              // 14 frags x 64 lanes x 4 u32
#define WS_HF0 4096
#define WS_HB0 (WS_HF0 + NE * TT * FRAG_T)
#define WS_END (WS_HB0 + NE * TT * FRAG_T)
#define PK1 0x00003C00u       // f16 pair {1.0, 0.0}

#define LOG2E  1.442695041f
#define LOG2E2 2.885390082f

typedef unsigned u32;
typedef __fp16 f16x8 __attribute__((ext_vector_type(8)));
typedef float   f32x16 __attribute__((ext_vector_type(16)));
typedef u32     u32x4 __attribute__((ext_vector_type(4)));
typedef __fp16  h2v   __attribute__((ext_vector_type(2)));

__device__ __forceinline__ u32 pk_h16(float a, float b) {
    h2v v = __builtin_amdgcn_cvt_pkrtz(a, b);
    return __builtin_bit_cast(u32, v);
}
__device__ __forceinline__ float unpk_hi_f16(u32 u) {
    return (float)__builtin_bit_cast(h2v, u)[1];
}
__device__ __forceinline__ f32x16 MFMA(u32x4 a, u32x4 b, f32x16 c) {
    return __builtin_amdgcn_mfma_f32_32x32x16_f16(
        __builtin_bit_cast(f16x8, a), __builtin_bit_cast(f16x8, b), c, 0, 0, 0);
}

// Combined-rcp LSTM unit (8 trans ops/unit).
__device__ __forceinline__ void unit_cr(float ai, float af, float ag, float ao,
                                        float* c, float* h) {
    float pi = __builtin_amdgcn_exp2f(-LOG2E * ai);
    float pf = __builtin_amdgcn_exp2f(-LOG2E * af);
    float q  = __builtin_amdgcn_exp2f(LOG2E2 * ag);
    float fv = __builtin_amdgcn_rcpf(1.0f + pf);
    float ig = (q - 1.0f) * __builtin_amdgcn_rcpf((1.0f + pi) * (q + 1.0f));
    float cv = fmaf(fv, *c, ig);
    *c = cv;
    float po = __builtin_amdgcn_exp2f(-LOG2E * ao);
    float qc = __builtin_amdgcn_exp2f(LOG2E2 * cv);
    *h = (qc - 1.0f) * __builtin_amdgcn_rcpf((1.0f + po) * (qc + 1.0f));
}

// h-input B-fragment; k = 4g+{0..3} U 8+4g+{0..3}.  One bpermute/pack.
__device__ __forceinline__ u32x4 pack_h(const float* h, bool hi, int xaddr, u32 b3) {
    u32 send = hi ? pk_h16(h[3], h[4]) : __float_as_uint(h[4]);
    u32 recv = (u32)__builtin_amdgcn_ds_bpermute(xaddr, (int)send);
    u32 lo0 = pk_h16(h[0], h[1]), lo1 = pk_h16(h[2], h[3]);
    u32 hi0 = pk_h16(__uint_as_float(recv), h[0]);   // {h4, h5}
    u32 hi1 = pk_h16(h[1], h[2]);                    // {h6, h7}
    u32x4 b;
    b[0] = hi ? hi0 : lo0;
    b[1] = hi ? hi1 : lo1;
    b[2] = hi ? 0u : recv;                           // {h8, h9} on g0
    b[3] = b3;
    return b;
}

// C layout (verified): row=(r&3)+8*(r>>2)+4*(lane>>5); row perm pi(q,u=5h+v).
__device__ __forceinline__ void cell_update5(const f32x16 a0, const f32x16 a1,
                                             float* c, float* h) {
#pragma unroll
    for (int v = 0; v < 4; ++v)
        unit_cr(a0[v], a0[4 + v], a0[8 + v], a0[12 + v], &c[v], &h[v]);
    unit_cr(a1[0], a1[1], a1[2], a1[3], &c[4], &h[4]);
}

// ---------------- prep: build A-fragments (weights, permuted rows) ----------------
__device__ __forceinline__ int inv_pi(int row) {
    if (row < 32) { int q = row >> 3, rem = row & 7; return q * 10 + 5 * (rem >> 2) + (rem & 3); }
    if (row < 40) { int lo = row - 32; return (lo & 3) * 10 + 5 * (lo >> 2) + 4; }
    return -1;
}

__global__ __launch_bounds__(256)
void prep_mfma(
    const float* __restrict__ wih0, const float* __restrict__ whh0,
    const float* __restrict__ bih0, const float* __restrict__ bhh0,
    const float* __restrict__ wih0r,const float* __restrict__ whh0r,
    const float* __restrict__ bih0r,const float* __restrict__ bhh0r,
    const float* __restrict__ wih1r,const float* __restrict__ whh1r,
    const float* __restrict__ bih1r,const float* __restrict__ bhh1r,
    u32* __restrict__ ws)
{
    for (int gid = threadIdx.x; gid < 14 * 64 * 4; gid += 256) {
        int fid = gid >> 8, l = (gid >> 2) & 63, j = gid & 3;
        int g = l >> 5;
        int tile, chunk;
        if (fid < 8) { tile = (fid >> 1) & 1; chunk = fid & 1; }
        else         { int q = fid - 8; tile = q / 3; chunk = q % 3; }
        int row = tile * 32 + (l & 31);
        int orow = inv_pi(row);
        int kb = (j >> 1) * 8 + 4 * g + (j & 1) * 2;
        float v[2] = {0.f, 0.f};
        if (orow >= 0) {
#pragma unroll
            for (int s = 0; s < 2; ++s) {
                int k = kb + s;
                float val = 0.f;
                if (fid < 8) {
                    bool bwd = fid >= 4;
                    if (chunk == 0) {
                        if (k < 6)       val = (bwd ? wih0r : wih0)[orow * 6 + k];
                        else if (k == 6) val = (bwd ? bih0r[orow] + bhh0r[orow]
                                                    : bih0[orow] + bhh0[orow]);
                    } else {
                        if (k < 10)      val = (bwd ? whh0r : whh0)[orow * 10 + k];
                    }
                } else {
                    if (chunk == 0)      { if (k < 10) val = wih1r[orow * 20 + k]; }
                    else if (chunk == 1) { if (k < 10) val = wih1r[orow * 20 + 10 + k]; }
                    else {
                        if (k < 10)      val = whh1r[orow * 10 + k];
                        else if (k == 10) val = bih1r[orow] + bhh1r[orow];
                    }
                }
                v[s] = val;
            }
        }
        ws[WS_WGT + (fid * 64 + l) * 4 + j] = pk_h16(v[0], v[1]);
    }
}

// ------------- fused kernel: 4 waves/block = {fwd,bwd} x 2 groups -------------
// Phase A: fwd-wave and bwd-wave run layer-0 chains concurrently (frags -> ws).
// Phase B: fwd-wave runs layer-1 backward chain (reads frags from ws).
struct FusedLds { uint2 bx[2][TT][64]; };   // 20480 B: pre-selected x frag words

__global__ __launch_bounds__(256, 4)
void bilstm_fused4(
    const int*   __restrict__ eidx, const float* __restrict__ f,
    const float* __restrict__ emb,  const float* __restrict__ fw,
    const float* __restrict__ fb,
    const u32* __restrict__ wsr, u32* __restrict__ ghf, u32* __restrict__ ghb,
    float* __restrict__ out)
{
    __shared__ FusedLds lds;
    const int  tid  = threadIdx.x;
    const int  lane = tid & 63;
    const int  e    = lane & 31;
    const bool hi   = lane >= 32;
    const int  wslot = __builtin_amdgcn_readfirstlane(tid >> 6);
    const int  gloc = wslot >> 1;          // group within block
    const int  role = wslot & 1;           // 0 = fwd (+CB), 1 = bwd
    const int  g    = blockIdx.x * 2 + gloc;
    const int  xaddr = (lane ^ 32) << 2;

    // ---- cooperative staging: both groups' x, pre-selected per lane ----
    {
        float fw0=fw[0],fw1=fw[1],fw2=fw[2],fw3=fw[3],fw4=fw[4];
        float fw5=fw[5],fw6=fw[6],fw7=fw[7],fw8=fw[8];
        float fb0=fb[0],fb1=fb[1],fb2=fb[2];
#pragma unroll 1
        for (int it = 0; it < 5; ++it) {
            int ii = tid + it * 256;             // 0..1279
            int gl = ii / 640, rem = ii - gl * 640;
            int ee = rem / 20, t = rem - ee * 20;
            int gi = ((blockIdx.x * 2 + gl) * 32 + ee) * TT + t;
            float f0 = f[gi * 3], f1 = f[gi * 3 + 1], f2v = f[gi * 3 + 2];
            int ei = eidx[gi] * 3;
            float x0 = emb[ei], x1 = emb[ei + 1], x2 = emb[ei + 2];
            float x3 = fmaf(fw0, f0, fmaf(fw1, f1, fmaf(fw2, f2v, fb0)));
            float x4 = fmaf(fw3, f0, fmaf(fw4, f1, fmaf(fw5, f2v, fb1)));
            float x5 = fmaf(fw6, f0, fmaf(fw7, f1, fmaf(fw8, f2v, fb2)));
            float m  = (f1 != 0.f) ? 1.f : 0.f;
            lds.bx[gl][t][ee]      = make_uint2(pk_h16(x0, x1), pk_h16(x2, x3));
            lds.bx[gl][t][ee + 32] = make_uint2(pk_h16(x4, x5), pk_h16(1.0f, m));
        }   // hi-lane word1 = {bias=1.0 @k6, mask @k7}; weight rows are 0 at k7.
    }
    __syncthreads();

    const u32x4* wv = (const u32x4*)wsr;
    const f32x16 zf = {};

    // ---- Phase A: layer-0 chain (fwd or bwd by role), frags to ws ----
    {
        const int wbase = role ? 4 : 0;
        u32x4 w0 = wv[(wbase + 0) * 64 + lane], w1 = wv[(wbase + 1) * 64 + lane];
        u32x4 w2 = wv[(wbase + 2) * 64 + lane], w3 = wv[(wbase + 3) * 64 + lane];
        u32* outp = (role ? ghb : ghf) + (size_t)g * TT * FRAG_T;
        const int t0 = role ? TT - 1 : 0;
        const int dt = role ? -1 : 1;

        float cst[5] = {0,0,0,0,0}, hv[5] = {0,0,0,0,0};
        uint2 bw = lds.bx[gloc][t0][lane];
        u32x4 bx; bx[0] = bw.x; bx[1] = bw.y; bx[2] = 0u; bx[3] = 0u;
        f32x16 a0x = MFMA(w0, bx, zf);
        f32x16 a1x = MFMA(w2, bx, zf);
        u32x4 bh;
#pragma unroll 1
        for (int s = 0; s < TT; ++s) {
            const int t = t0 + s * dt;
            f32x16 a0 = a0x, a1 = a1x;
            if (s > 0) { a0 = MFMA(w1, bh, a0); a1 = MFMA(w3, bh, a1); }
            if (s + 1 < TT) {
                bw = lds.bx[gloc][t + dt][lane];
                bx[0] = bw.x; bx[1] = bw.y;
                a0x = MFMA(w0, bx, zf);
                a1x = MFMA(w2, bx, zf);
            }
            cell_update5(a0, a1, cst, hv);
            bh = pack_h(hv, hi, xaddr, 0u);
            *(uint2*)(outp + t * FRAG_T + lane * 2) = make_uint2(bh[0], bh[1]);
            if (!hi) outp[t * FRAG_T + 128 + e] = bh[2];
        }
    }
    __syncthreads();   // drains vmem: hb/hf frags visible to phase B

    // ---- Phase B: layer-1 backward chain (fwd-waves only) ----
    if (role == 0) {
        u32x4 wB0 = wv[8 * 64 + lane],  wB1 = wv[9 * 64 + lane],  wB2 = wv[10 * 64 + lane];
        u32x4 wB3 = wv[11 * 64 + lane], wB4 = wv[12 * 64 + lane], wB5 = wv[13 * 64 + lane];
        const u32* hfp = ghf + (size_t)g * TT * FRAG_T;
        const u32* hbp = ghb + (size_t)g * TT * FRAG_T;
        const int b0 = g * 32;
        float cc[5] = {0,0,0,0,0}, h1v[5] = {0,0,0,0,0}, tot = 0.f;

        uint2 hf2 = *(const uint2*)(hfp + (TT - 1) * FRAG_T + lane * 2);
        u32   hfw = hfp[(TT - 1) * FRAG_T + 128 + e];
        uint2 hb2 = *(const uint2*)(hbp + (TT - 1) * FRAG_T + lane * 2);
        u32   hbw = hbp[(TT - 1) * FRAG_T + 128 + e];

#pragma unroll 1
        for (int t = TT - 1; t >= 0; --t) {
            u32x4 bhf; bhf[0] = hf2.x; bhf[1] = hf2.y; bhf[2] = hi ? 0u : hfw; bhf[3] = 0u;
            u32x4 bhb; bhb[0] = hb2.x; bhb[1] = hb2.y; bhb[2] = hi ? 0u : hbw; bhb[3] = 0u;
            f32x16 B0 = MFMA(wB0, bhf, zf); B0 = MFMA(wB1, bhb, B0);
            f32x16 B1 = MFMA(wB3, bhf, zf); B1 = MFMA(wB4, bhb, B1);
            if (t > 0) {                        // prefetch t-1 frags
                hf2 = *(const uint2*)(hfp + (t - 1) * FRAG_T + lane * 2);
                hfw = hfp[(t - 1) * FRAG_T + 128 + e];
                hb2 = *(const uint2*)(hbp + (t - 1) * FRAG_T + lane * 2);
                hbw = hbp[(t - 1) * FRAG_T + 128 + e];
            }
            u32x4 bh1 = pack_h(h1v, hi, xaddr, hi ? 0u : PK1);
            B0 = MFMA(wB2, bh1, B0);
            B1 = MFMA(wB5, bh1, B1);
            cell_update5(B0, B1, cc, h1v);
            if (hi) {                           // unit 9 = (half1, v=4)
                float m  = unpk_hi_f16(lds.bx[gloc][t][lane].y);  // staged mask
                float ip = fmaxf(h1v[4] * m, 0.f);
                out[BB + (b0 + e) * TT + t] = ip;
                tot += ip;
            }
        }
        if (hi) out[b0 + e] = tot;
    }
}

// ---------------- fallback: r9 single-kernel, LDS-only (small ws) ----------------
struct LdsFB {
    u32   x[TT][3][32];
    float m[TT][32];
    u32   hf[TT][FRAG_T];
};

__global__ __launch_bounds__(64)
void bilstm_fb(
    const int*   __restrict__ eidx, const float* __restrict__ f,
    const float* __restrict__ emb,  const float* __restrict__ fw,
    const float* __restrict__ fb,
    const u32* __restrict__ wsr, float* __restrict__ out)
{
    __shared__ LdsFB lds;
    const int  lane = threadIdx.x;
    const int  e    = lane & 31;
    const bool hi   = lane >= 32;
    const int  wid  = blockIdx.x;
    const int  b0   = wid * 32;
    const int  xaddr = (lane ^ 32) << 2;
    {
        float fw0=fw[0],fw1=fw[1],fw2=fw[2],fw3=fw[3],fw4=fw[4];
        float fw5=fw[5],fw6=fw[6],fw7=fw[7],fw8=fw[8];
        float fb0=fb[0],fb1=fb[1],fb2=fb[2];
#pragma unroll 1
        for (int it = 0; it < 10; ++it) {
            int idx = lane + it * 64;
            int ee = idx / 20, t = idx - ee * 20;
            int gi = (b0 + ee) * TT + t;
            float f0 = f[gi * 3], f1 = f[gi * 3 + 1], f2v = f[gi * 3 + 2];
            int ei = eidx[gi] * 3;
            float x0 = emb[ei], x1 = emb[ei + 1], x2 = emb[ei + 2];
            float x3 = fmaf(fw0, f0, fmaf(fw1, f1, fmaf(fw2, f2v, fb0)));
            float x4 = fmaf(fw3, f0, fmaf(fw4, f1, fmaf(fw5, f2v, fb1)));
            float x5 = fmaf(fw6, f0, fmaf(fw7, f1, fmaf(fw8, f2v, fb2)));
            lds.x[t][0][ee] = pk_h16(x0, x1);
            lds.x[t][1][ee] = pk_h16(x2, x3);
            lds.x[t][2][ee] = pk_h16(x4, x5);
            lds.m[t][ee]    = (f1 != 0.f) ? 1.f : 0.f;
        }
    }
    const u32x4* wv = (const u32x4*)wsr;
    const f32x16 zf = {};
    {
        u32x4 wf0 = wv[0 * 64 + lane], wf1 = wv[1 * 64 + lane];
        u32x4 wf2 = wv[2 * 64 + lane], wf3 = wv[3 * 64 + lane];
        float cf[5] = {0,0,0,0,0}, hv[5] = {0,0,0,0,0};
        u32x4 bx0;
        {
            u32 x01 = lds.x[0][0][e], x23 = lds.x[0][1][e], x45 = lds.x[0][2][e];
            bx0[0] = hi ? x45 : x01; bx0[1] = hi ? PK1 : x23; bx0[2] = 0u; bx0[3] = 0u;
        }
        f32x16 a0x = MFMA(wf0, bx0, zf);
        f32x16 a1x = MFMA(wf2, bx0, zf);
        u32x4 bh;
#pragma unroll 1
        for (int t = 0; t < TT; ++t) {
            f32x16 a0 = a0x, a1 = a1x;
            if (t > 0) { a0 = MFMA(wf1, bh, a0); a1 = MFMA(wf3, bh, a1); }
            if (t + 1 < TT) {
                u32 x01 = lds.x[t+1][0][e], x23 = lds.x[t+1][1][e], x45 = lds.x[t+1][2][e];
                u32x4 bx; bx[0] = hi ? x45 : x01; bx[1] = hi ? PK1 : x23; bx[2] = 0u; bx[3] = 0u;
                a0x = MFMA(wf0, bx, zf);
                a1x = MFMA(wf2, bx, zf);
            }
            cell_update5(a0, a1, cf, hv);
            bh = pack_h(hv, hi, xaddr, 0u);
            lds.hf[t][lane * 2] = bh[0]; lds.hf[t][lane * 2 + 1] = bh[1];
            if (!hi) lds.hf[t][128 + e] = bh[2];
        }
    }
    {
        u32x4 wb0 = wv[4 * 64 + lane], wb1 = wv[5 * 64 + lane];
        u32x4 wb2 = wv[6 * 64 + lane], wb3 = wv[7 * 64 + lane];
        u32x4 wB0 = wv[8 * 64 + lane], wB1 = wv[9 * 64 + lane], wB2 = wv[10 * 64 + lane];
        u32x4 wB3 = wv[11 * 64 + lane], wB4 = wv[12 * 64 + lane], wB5 = wv[13 * 64 + lane];
        float cb[5] = {0,0,0,0,0}, hbv[5] = {0,0,0,0,0};
        float cc[5] = {0,0,0,0,0}, h1v[5] = {0,0,0,0,0};
        float tot = 0.f;
        {
            u32 x01 = lds.x[TT-1][0][e], x23 = lds.x[TT-1][1][e], x45 = lds.x[TT-1][2][e];
            u32x4 bx; bx[0] = hi ? x45 : x01; bx[1] = hi ? PK1 : x23; bx[2] = 0u; bx[3] = 0u;
            f32x16 a0 = MFMA(wb0, bx, zf);
            f32x16 a1 = MFMA(wb2, bx, zf);
            cell_update5(a0, a1, cb, hbv);
        }
        uint2 cur2 = make_uint2(lds.hf[TT-1][lane * 2], lds.hf[TT-1][lane * 2 + 1]);
        u32   curw = lds.hf[TT-1][128 + e];
#pragma unroll 1
        for (int t = TT - 1; t >= 1; --t) {
            uint2 nxt2 = make_uint2(lds.hf[t-1][lane * 2], lds.hf[t-1][lane * 2 + 1]);
            u32   nxtw = lds.hf[t-1][128 + e];
            u32x4 shared = pack_h(hbv, hi, xaddr, 0u);
            u32x4 bh1    = pack_h(h1v, hi, xaddr, hi ? 0u : PK1);
            u32x4 bhf; bhf[0] = cur2.x; bhf[1] = cur2.y; bhf[2] = hi ? 0u : curw; bhf[3] = 0u;
            f32x16 B0 = MFMA(wB0, bhf, zf); B0 = MFMA(wB1, shared, B0); B0 = MFMA(wB2, bh1, B0);
            f32x16 B1 = MFMA(wB3, bhf, zf); B1 = MFMA(wB4, shared, B1); B1 = MFMA(wB5, bh1, B1);
            u32 x01 = lds.x[t-1][0][e], x23 = lds.x[t-1][1][e], x45 = lds.x[t-1][2][e];
            u32x4 bx; bx[0] = hi ? x45 : x01; bx[1] = hi ? PK1 : x23; bx[2] = 0u; bx[3] = 0u;
            f32x16 A0 = MFMA(wb0, bx, zf); A0 = MFMA(wb1, shared, A0);
            f32x16 A1 = MFMA(wb2, bx, zf); A1 = MFMA(wb3, shared, A1);
            cell_update5(B0, B1, cc, h1v);
            if (hi) {
                float ip = fmaxf(h1v[4] * lds.m[t][e], 0.f);
                out[BB + (b0 + e) * TT + t] = ip;
                tot += ip;
            }
            cell_update5(A0, A1, cb, hbv);
            cur2 = nxt2; curw = nxtw;
        }
        {
            u32x4 shared = pack_h(hbv, hi, xaddr, 0u);
            u32x4 bh1    = pack_h(h1v, hi, xaddr, hi ? 0u : PK1);
            u32x4 bhf; bhf[0] = cur2.x; bhf[1] = cur2.y; bhf[2] = hi ? 0u : curw; bhf[3] = 0u;
            f32x16 B0 = MFMA(wB0, bhf, zf); B0 = MFMA(wB1, shared, B0); B0 = MFMA(wB2, bh1, B0);
            f32x16 B1 = MFMA(wB3, bhf, zf); B1 = MFMA(wB4, shared, B1); B1 = MFMA(wB5, bh1, B1);
            cell_update5(B0, B1, cc, h1v);
            if (hi) {
                float ip = fmaxf(h1v[4] * lds.m[0][e], 0.f);
                out[BB + (b0 + e) * TT + 0] = ip;
                tot += ip;
                out[b0 + e] = tot;
            }
        }
    }
}

extern "C" void kernel_launch(void* const* d_in, const int* in_sizes, int n_in,
                              void* d_out, int out_size, void* d_ws, size_t ws_size,
                              hipStream_t stream) {
    const int*   eidx  = (const int*)  d_in[0];
    const float* f     = (const float*)d_in[1];
    const float* emb   = (const float*)d_in[2];
    const float* fw    = (const float*)d_in[3];
    const float* fb    = (const float*)d_in[4];
    const float* wih0  = (const float*)d_in[5];
    const float* whh0  = (const float*)d_in[6];
    const float* bih0  = (const float*)d_in[7];
    const float* bhh0  = (const float*)d_in[8];
    const float* wih0r = (const float*)d_in[9];
    const float* whh0r = (const float*)d_in[10];
    const float* bih0r = (const float*)d_in[11];
    const float* bhh0r = (const float*)d_in[12];
    // d_in[13..16] = layer-1 forward weights: dead (output uses only bwd unit 9)
    const float* wih1r = (const float*)d_in[17];
    const float* whh1r = (const float*)d_in[18];
    const float* bih1r = (const float*)d_in[19];
    const float* bhh1r = (const float*)d_in[20];
    float* out = (float*)d_out;
    u32* ws = (u32*)d_ws;

    hipLaunchKernelGGL(prep_mfma, dim3(1), dim3(256), 0, stream,
                       wih0, whh0, bih0, bhh0, wih0r, whh0r, bih0r, bhh0r,
                       wih1r, whh1r, bih1r, bhh1r, ws);

    if (ws_size >= (size_t)WS_END * 4) {
        hipLaunchKernelGGL(bilstm_fused4, dim3(NE / 2), dim3(256), 0, stream,
                           eidx, f, emb, fw, fb, ws, ws + WS_HF0, ws + WS_HB0, out);
    } else {
        hipLaunchKernelGGL(bilstm_fb, dim3(NE), dim3(64), 0, stream,
                           eidx, f, emb, fw, fb, ws, out);
    }
}